// Round 2
// baseline (100.895 us; speedup 1.0000x reference)
//
#include <hip/hip_runtime.h>
#include <hip/hip_fp16.h>
#include <math.h>

#define NHEADS 16
#define HD 64
#define DMODEL 1024
#define TOKW 4            // tokens (=waves) per block

// Per-token LDS layout (float offsets). Pads kill >2-way bank conflicts.
//  q : 16 rows x 36 floats (64 halves used = 32 fl, + pad)   [   0,  576)
//  k : 16 rows x 36                                          [ 576, 1152)
//  v : 16 rows x 68 floats (64 fl + 4 pad)                   [1152, 2240)
//  p : 16 rows x 20 floats (16 fl + 4 pad)                   [2240, 2560)
#define TOKF 2560

union F4H {
    float4  f;
    __half2 h[4];
};

__device__ __forceinline__ void fma4(float4& o, float p, const float4& v) {
    o.x = fmaf(p, v.x, o.x);
    o.y = fmaf(p, v.y, o.y);
    o.z = fmaf(p, v.z, o.z);
    o.w = fmaf(p, v.w, o.w);
}

__global__ __launch_bounds__(256) void temporal_attn_kernel(
    const float* __restrict__ q,
    const float* __restrict__ k,
    const float* __restrict__ v,
    float* __restrict__ out)
{
    __shared__ float smem[TOKW * TOKF];

    const int wave = threadIdx.x >> 6;
    const int lane = threadIdx.x & 63;
    const size_t base = ((size_t)blockIdx.x * TOKW + wave) * DMODEL;

    float* qs = smem + wave * TOKF;
    float* ks = qs + 576;
    float* vs = qs + 1152;
    float* ps = qs + 2240;

    // ---------------- stage: coalesced global float4, q/k packed to fp16 ----------------
    const int si = lane >> 2;   // row 0..15
    const int sc = lane & 3;    // 16-float chunk 0..3
    const float4* qg = (const float4*)(q + base);
    const float4* kg = (const float4*)(k + base);
    const float4* vg = (const float4*)(v + base);
    float4 ql[4], kl[4], vl[4];
#pragma unroll
    for (int j = 0; j < 4; ++j) ql[j] = qg[4 * lane + j];
#pragma unroll
    for (int j = 0; j < 4; ++j) kl[j] = kg[4 * lane + j];
#pragma unroll
    for (int j = 0; j < 4; ++j) vl[j] = vg[4 * lane + j];

    F4H qh[2], kh[2];
#pragma unroll
    for (int j = 0; j < 2; ++j) {
        qh[j].h[0] = __floats2half2_rn(ql[2*j].x,   ql[2*j].y);
        qh[j].h[1] = __floats2half2_rn(ql[2*j].z,   ql[2*j].w);
        qh[j].h[2] = __floats2half2_rn(ql[2*j+1].x, ql[2*j+1].y);
        qh[j].h[3] = __floats2half2_rn(ql[2*j+1].z, ql[2*j+1].w);
        kh[j].h[0] = __floats2half2_rn(kl[2*j].x,   kl[2*j].y);
        kh[j].h[1] = __floats2half2_rn(kl[2*j].z,   kl[2*j].w);
        kh[j].h[2] = __floats2half2_rn(kl[2*j+1].x, kl[2*j+1].y);
        kh[j].h[3] = __floats2half2_rn(kl[2*j+1].z, kl[2*j+1].w);
    }
    // fp16 row = 144 B (36 fl); lane's 16 halves at fl-offset 8*sc
    *(float4*)&qs[36 * si + 8 * sc + 0] = qh[0].f;
    *(float4*)&qs[36 * si + 8 * sc + 4] = qh[1].f;
    *(float4*)&ks[36 * si + 8 * sc + 0] = kh[0].f;
    *(float4*)&ks[36 * si + 8 * sc + 4] = kh[1].f;
#pragma unroll
    for (int j = 0; j < 4; ++j)
        *(float4*)&vs[68 * si + 16 * sc + 4 * j] = vl[j];
    // wave-synchronous: no barrier needed (LDS slice is private to this wave;
    // compiler orders ds_write -> ds_read via lgkmcnt)

    // ---------------- scores: 2x2 tile per lane, packed fp16 FMA ----------------
    const int ri = lane >> 3;   // row-pair 0..7  -> rows 2ri, 2ri+1
    const int ci = lane & 7;    // col-pair 0..7  -> cols 2ci, 2ci+1
    const __half2 z2 = __float2half2_rn(0.f);
    __half2 a00 = z2, a01 = z2, a10 = z2, a11 = z2;
#pragma unroll
    for (int d = 0; d < 8; ++d) {   // 8 chunks of 8 halves
        F4H qa, qb, ka, kb;
        qa.f = *(const float4*)&qs[36 * (2 * ri)     + 4 * d];
        qb.f = *(const float4*)&qs[36 * (2 * ri + 1) + 4 * d];
        ka.f = *(const float4*)&ks[36 * (2 * ci)     + 4 * d];
        kb.f = *(const float4*)&ks[36 * (2 * ci + 1) + 4 * d];
#pragma unroll
        for (int m = 0; m < 4; ++m) {
            a00 = __hfma2(qa.h[m], ka.h[m], a00);
            a01 = __hfma2(qa.h[m], kb.h[m], a01);
            a10 = __hfma2(qb.h[m], ka.h[m], a10);
            a11 = __hfma2(qb.h[m], kb.h[m], a11);
        }
    }
    float s00 = (__low2float(a00) + __high2float(a00)) * 0.125f;
    float s01 = (__low2float(a01) + __high2float(a01)) * 0.125f;
    float s10 = (__low2float(a10) + __high2float(a10)) * 0.125f;
    float s11 = (__low2float(a11) + __high2float(a11)) * 0.125f;
    // causal over heads: col > row -> -inf
    {
        const int r0 = 2 * ri, r1 = 2 * ri + 1, c0 = 2 * ci, c1 = 2 * ci + 1;
        if (c0 > r0) s00 = -1e30f;
        if (c1 > r0) s01 = -1e30f;
        if (c0 > r1) s10 = -1e30f;
        if (c1 > r1) s11 = -1e30f;
    }
    // softmax over the 16 cols = 8 ci-lanes x 2 values, per row a=0,1
#pragma unroll
    for (int a = 0; a < 2; ++a) {
        float x0 = a ? s10 : s00;
        float x1 = a ? s11 : s01;
        float m = fmaxf(x0, x1);
        m = fmaxf(m, __shfl_xor(m, 1));
        m = fmaxf(m, __shfl_xor(m, 2));
        m = fmaxf(m, __shfl_xor(m, 4));
        float e0 = __expf(x0 - m);
        float e1 = __expf(x1 - m);
        float sum = e0 + e1;
        sum += __shfl_xor(sum, 1);
        sum += __shfl_xor(sum, 2);
        sum += __shfl_xor(sum, 4);
        const float inv = 1.0f / sum;
        float2 pw = make_float2(e0 * inv, e1 * inv);
        *(float2*)&ps[20 * (2 * ri + a) + 2 * ci] = pw;
    }

    // ---------------- PV: lane owns rows {r4, 4+r4, 8+r4, 12+r4}, cols 4*c4..+3 ----------------
    const int r4 = lane >> 4;   // 0..3
    const int c4 = lane & 15;   // 0..15
    float4 o0 = make_float4(0.f, 0.f, 0.f, 0.f);
    float4 o1 = o0, o2 = o0, o3 = o0;
#pragma unroll
    for (int jb = 0; jb < 4; ++jb) {
        const float4 p0 = *(const float4*)&ps[20 * (0 + r4)  + 4 * jb];
        const float4 p1 = *(const float4*)&ps[20 * (4 + r4)  + 4 * jb];
        const float4 p2 = *(const float4*)&ps[20 * (8 + r4)  + 4 * jb];
        const float4 p3 = *(const float4*)&ps[20 * (12 + r4) + 4 * jb];
        float4 vj;
        vj = *(const float4*)&vs[68 * (4 * jb + 0) + 4 * c4];
        fma4(o0, p0.x, vj); fma4(o1, p1.x, vj); fma4(o2, p2.x, vj); fma4(o3, p3.x, vj);
        vj = *(const float4*)&vs[68 * (4 * jb + 1) + 4 * c4];
        fma4(o0, p0.y, vj); fma4(o1, p1.y, vj); fma4(o2, p2.y, vj); fma4(o3, p3.y, vj);
        vj = *(const float4*)&vs[68 * (4 * jb + 2) + 4 * c4];
        fma4(o0, p0.z, vj); fma4(o1, p1.z, vj); fma4(o2, p2.z, vj); fma4(o3, p3.z, vj);
        vj = *(const float4*)&vs[68 * (4 * jb + 3) + 4 * c4];
        fma4(o0, p0.w, vj); fma4(o1, p1.w, vj); fma4(o2, p2.w, vj); fma4(o3, p3.w, vj);
    }
    // coalesced stores: float4 index g = 64*jj + lane covers the token contiguously
    float4* og = (float4*)(out + base);
    og[0 * 64 + lane] = o0;
    og[1 * 64 + lane] = o1;
    og[2 * 64 + lane] = o2;
    og[3 * 64 + lane] = o3;
}

extern "C" void kernel_launch(void* const* d_in, const int* in_sizes, int n_in,
                              void* d_out, int out_size, void* d_ws, size_t ws_size,
                              hipStream_t stream) {
    const float* q = (const float*)d_in[0];
    const float* k = (const float*)d_in[1];
    const float* v = (const float*)d_in[2];
    float* o = (float*)d_out;
    const int ntok = in_sizes[0] / DMODEL;        // B*S
    const int nblk = ntok / TOKW;                 // 32768/4 = 8192
    temporal_attn_kernel<<<nblk, 256, 0, stream>>>(q, k, v, o);
}

// Round 3
// 96.885 us; speedup vs baseline: 1.0414x; 1.0414x over previous
//
#include <hip/hip_runtime.h>
#include <math.h>

#define DMODEL 1024   // 16 heads x 64 dim
#define TOKW 4        // one wave per token, 4 waves per block

typedef _Float16 f16x4 __attribute__((ext_vector_type(4)));
typedef _Float16 f16x8 __attribute__((ext_vector_type(8)));
typedef float    f32x4 __attribute__((ext_vector_type(4)));

__global__ __launch_bounds__(256) void temporal_attn_kernel(
    const float* __restrict__ q,
    const float* __restrict__ k,
    const float* __restrict__ v,
    float* __restrict__ out)
{
    const int lane = threadIdx.x & 63;
    const int wave = threadIdx.x >> 6;
    const int r = lane & 15;   // head row 0..15
    const int G = lane >> 4;   // lane group 0..3
    const size_t base = ((size_t)blockIdx.x * TOKW + wave) * DMODEL;

    // ---------------- issue ALL global loads up front ----------------
    // q/k fragment gather: lane needs row r, d = 32c + 8G + {0..7}  (2 float4 per chunk)
    const float* qrow = q + base + r * 64;
    const float* krow = k + base + r * 64;
    f32x4 ql[4], kl[4];
#pragma unroll
    for (int c = 0; c < 2; ++c)
#pragma unroll
        for (int h = 0; h < 2; ++h) {
            ql[2 * c + h] = *(const f32x4*)(qrow + 32 * c + 8 * G + 4 * h);
            kl[2 * c + h] = *(const f32x4*)(krow + 32 * c + 8 * G + 4 * h);
        }
    // v fragment gather: vl[t][cg] = v[4G+t][16cg + r]  (each 64B line fetched once)
    float vl[4][4];
#pragma unroll
    for (int t = 0; t < 4; ++t)
#pragma unroll
        for (int cg = 0; cg < 4; ++cg)
            vl[t][cg] = v[base + (size_t)(4 * G + t) * 64 + 16 * cg + r];

    // ---------------- QK^T as S^T = K * Q^T  (2x mfma 16x16x32 f16) ----------------
    f16x8 ka[2], qb[2];
#pragma unroll
    for (int c = 0; c < 2; ++c)
#pragma unroll
        for (int h = 0; h < 2; ++h)
#pragma unroll
            for (int e = 0; e < 4; ++e) {
                ka[c][4 * h + e] = (_Float16)kl[2 * c + h][e];
                qb[c][4 * h + e] = (_Float16)ql[2 * c + h][e];
            }

    f32x4 acc = {0.f, 0.f, 0.f, 0.f};
    acc = __builtin_amdgcn_mfma_f32_16x16x32_f16(ka[0], qb[0], acc, 0, 0, 0);
    acc = __builtin_amdgcn_mfma_f32_16x16x32_f16(ka[1], qb[1], acc, 0, 0, 0);
    // lane now holds S[i = r][j = 4G + e], e = 0..3

    // ---------------- causal softmax over j (regs + xor16 + xor32) ----------------
    float s[4];
#pragma unroll
    for (int e = 0; e < 4; ++e) {
        const int j = 4 * G + e;
        s[e] = (j > r) ? -1e30f : acc[e] * 0.125f;   // 1/sqrt(64)
    }
    float m = fmaxf(fmaxf(s[0], s[1]), fmaxf(s[2], s[3]));
    m = fmaxf(m, __shfl_xor(m, 16));
    m = fmaxf(m, __shfl_xor(m, 32));
    const float e0 = __expf(s[0] - m);
    const float e1 = __expf(s[1] - m);
    const float e2 = __expf(s[2] - m);
    const float e3 = __expf(s[3] - m);
    float sum = e0 + e1 + e2 + e3;
    sum += __shfl_xor(sum, 16);
    sum += __shfl_xor(sum, 32);
    const float inv = 1.0f / sum;
    // P already in the A-fragment layout for 16x16x16: A[r][4G + t]
    f16x4 pa;
    pa[0] = (_Float16)(e0 * inv);
    pa[1] = (_Float16)(e1 * inv);
    pa[2] = (_Float16)(e2 * inv);
    pa[3] = (_Float16)(e3 * inv);

    // ---------------- PV: out[:, 16cg:16cg+16] = P * V  (4x mfma 16x16x16 f16) ----------------
#pragma unroll
    for (int cg = 0; cg < 4; ++cg) {
        f16x4 vb;
#pragma unroll
        for (int t = 0; t < 4; ++t) vb[t] = (_Float16)vl[t][cg];
        f32x4 o = {0.f, 0.f, 0.f, 0.f};
        o = __builtin_amdgcn_mfma_f32_16x16x16f16(pa, vb, o, 0, 0, 0);
        // D[row = 4G+e][col = 16cg + r] -> coalesced scalar stores (4x64B per instr)
        float* obase = out + base + (size_t)(4 * G) * 64 + 16 * cg + r;
#pragma unroll
        for (int e = 0; e < 4; ++e)
            obase[e * 64] = o[e];
    }
}

extern "C" void kernel_launch(void* const* d_in, const int* in_sizes, int n_in,
                              void* d_out, int out_size, void* d_ws, size_t ws_size,
                              hipStream_t stream) {
    const float* q = (const float*)d_in[0];
    const float* k = (const float*)d_in[1];
    const float* v = (const float*)d_in[2];
    float* o = (float*)d_out;
    const int ntok = in_sizes[0] / DMODEL;   // B*S
    temporal_attn_kernel<<<ntok / TOKW, 256, 0, stream>>>(q, k, v, o);
}